// Round 1
// baseline (92.623 us; speedup 1.0000x reference)
//
#include <hip/hip_runtime.h>
#include <hip/hip_bf16.h>

typedef __attribute__((ext_vector_type(8))) short short8;
typedef __attribute__((ext_vector_type(4))) float f32x4;

#define NW 16384
#define SB_STRIDE_U 68   // uints per (o,k) row: 64 data (128 bf16) + 4 pad

union U8 { unsigned int u[4]; short8 s; };

static __device__ __forceinline__ unsigned int pkbf(float a, float b) {
    float2 t; t.x = a; t.y = b;
    __hip_bfloat162 h = __float22bfloat162_rn(t);   // v_cvt_pk_bf16_f32
    unsigned int r; __builtin_memcpy(&r, &h, 4);
    return r;
}

// grid = 256 blocks x 512 threads (8 waves). ot = blockIdx&7 (XCD round-robin:
// 32 blocks per XCD share one L2-resident 64KB genW slice), bg = blockIdx>>3
// -> 128 b-rows per block, 16 per wave.
__global__ __launch_bounds__(512, 2) void hypernet_fused(
    const float* __restrict__ x,        // (4096,128)
    const float* __restrict__ feat,     // (4096,10)
    const float* __restrict__ fc0W, const float* __restrict__ fc0b,
    const float* __restrict__ a0p,
    const float* __restrict__ fc1W, const float* __restrict__ fc1b,
    const float* __restrict__ a1p,
    const float* __restrict__ genW,     // (16512,8)
    const float* __restrict__ genb,     // (16512)
    float* __restrict__ out)            // (4096,128)
{
    __shared__ __attribute__((aligned(16))) unsigned int sB32[16 * 9 * SB_STRIDE_U]; // 39168 B
    __shared__ float sH[128][8];                                                     // 4 KB

    const int tid  = threadIdx.x;
    const int ot   = blockIdx.x & 7;
    const int bg   = blockIdx.x >> 3;
    const int b0   = bg * 128;
    const int lane = tid & 63;
    const int w    = tid >> 6;          // wave 0..7
    const int quad = lane >> 4;
    const int o16  = lane & 15;
    const int o    = ot * 16 + o16;

    // ---- issue latency-critical independent loads EARLY ----
    float4 araw[8];
    const int arow = b0 + w * 16 + o16;
    #pragma unroll
    for (int kc = 0; kc < 4; kc++) {
        const float4* xp = (const float4*)(x + (size_t)arow * 128 + kc * 32 + quad * 8);
        araw[2 * kc]     = xp[0];
        araw[2 * kc + 1] = xp[1];
    }
    const float4* gt4 = (const float4*)(genW + (size_t)(NW + o) * 8);
    const float4 g0 = gt4[0], g1 = gt4[1];
    const float gbt = genb[NW + o];

    // ---- stage genW o-slice -> sB[o][k][i] bf16; paired-i b32 writes ----
    // 16 o x 128 i rows of 8 k-floats = 1024 i-pairs; 512 threads -> 2 each
    const float4* gw4 = (const float4*)(genW + (size_t)ot * 2048 * 8);
    #pragma unroll
    for (int j = 0; j < 2; j++) {
        const int idx = j * 512 + tid;              // [0,1024): oo = idx>>6, ip = idx&63
        const int oo = idx >> 6, ip = idx & 63;
        const int f4 = (oo * 128 + 2 * ip) * 2;
        const float4 p0 = gw4[f4], p1 = gw4[f4 + 1];     // i:   k0..3, k4..7
        const float4 q0 = gw4[f4 + 2], q1 = gw4[f4 + 3]; // i+1: k0..3, k4..7
        unsigned int* dst = sB32 + oo * 9 * SB_STRIDE_U + ip;
        dst[0 * SB_STRIDE_U] = pkbf(p0.x, q0.x);
        dst[1 * SB_STRIDE_U] = pkbf(p0.y, q0.y);
        dst[2 * SB_STRIDE_U] = pkbf(p0.z, q0.z);
        dst[3 * SB_STRIDE_U] = pkbf(p0.w, q0.w);
        dst[4 * SB_STRIDE_U] = pkbf(p1.x, q1.x);
        dst[5 * SB_STRIDE_U] = pkbf(p1.y, q1.y);
        dst[6 * SB_STRIDE_U] = pkbf(p1.z, q1.z);
        dst[7 * SB_STRIDE_U] = pkbf(p1.w, q1.w);
    }
    // ---- genb o-slice -> k=8 plane (1024 float2, 2 per thread) ----
    const float2* gb2 = (const float2*)(genb + (size_t)ot * 2048);
    #pragma unroll
    for (int j = 0; j < 2; j++) {
        const int idx = j * 512 + tid;
        const int oo = idx >> 6, ip = idx & 63;
        const float2 p = gb2[oo * 64 + ip];
        sB32[(oo * 9 + 8) * SB_STRIDE_U + ip] = pkbf(p.x, p.y);
    }
    // ---- tiny MLP -> sH (128 rows, one thread each) ----
    if (tid < 128) {
        const int b = b0 + tid;
        const float a0 = a0p[0], a1 = a1p[0];
        float fv[10];
        #pragma unroll
        for (int m = 0; m < 10; m++) fv[m] = feat[(size_t)b * 10 + m];
        float h0[16];
        #pragma unroll
        for (int jj = 0; jj < 16; jj++) {
            float t = fc0b[jj];
            #pragma unroll
            for (int m = 0; m < 10; m++) t += fc0W[jj * 10 + m] * fv[m];
            h0[jj] = (t >= 0.f) ? t : a0 * t;
        }
        #pragma unroll
        for (int n = 0; n < 8; n++) {
            float t = fc1b[n];
            #pragma unroll
            for (int jj = 0; jj < 16; jj++) t += fc1W[n * 16 + jj] * h0[jj];
            sH[tid][n] = (t >= 0.f) ? t : a1 * t;
        }
    }
    // ---- convert A-fragments (loads already landed) ----
    short8 a[4];
    #pragma unroll
    for (int kc = 0; kc < 4; kc++) {
        U8 t;
        const float4 va = araw[2 * kc], vb = araw[2 * kc + 1];
        t.u[0] = pkbf(va.x, va.y);
        t.u[1] = pkbf(va.z, va.w);
        t.u[2] = pkbf(vb.x, vb.y);
        t.u[3] = pkbf(vb.z, vb.w);
        a[kc] = t.s;
    }
    __syncthreads();

    // ---- main: 36 MFMAs per wave (16b x 16o x 9 k-planes, K=128) ----
    const unsigned short* sBs = (const unsigned short*)sB32;
    f32x4 acc[9];
    #pragma unroll
    for (int k = 0; k < 9; k++) acc[k] = (f32x4){0.f, 0.f, 0.f, 0.f};

    #pragma unroll
    for (int k = 0; k < 9; k++) {
        const unsigned short* bp = sBs + (o16 * 9 + k) * (SB_STRIDE_U * 2) + quad * 8;
        const short8 bv0 = *(const short8*)(bp);
        const short8 bv1 = *(const short8*)(bp + 32);
        const short8 bv2 = *(const short8*)(bp + 64);
        const short8 bv3 = *(const short8*)(bp + 96);
        acc[k] = __builtin_amdgcn_mfma_f32_16x16x32_bf16(a[0], bv0, acc[k], 0, 0, 0);
        acc[k] = __builtin_amdgcn_mfma_f32_16x16x32_bf16(a[1], bv1, acc[k], 0, 0, 0);
        acc[k] = __builtin_amdgcn_mfma_f32_16x16x32_bf16(a[2], bv2, acc[k], 0, 0, 0);
        acc[k] = __builtin_amdgcn_mfma_f32_16x16x32_bf16(a[3], bv3, acc[k], 0, 0, 0);
    }

    // ---- epilogue: out[b,o] = sum_{k<8} h1[b,k]*(Y_k + gW_tail[k]) + Y_8 + gb_tail ----
    const float gtv[8] = {g0.x, g0.y, g0.z, g0.w, g1.x, g1.y, g1.z, g1.w};
    const int brow0 = w * 16 + quad * 4;    // C/D: row = quad*4 + reg
    #pragma unroll
    for (int r = 0; r < 4; r++) {
        const float4* hp4 = (const float4*)sH[brow0 + r];
        const float4 ha = hp4[0], hb = hp4[1];
        const float hv[8] = {ha.x, ha.y, ha.z, ha.w, hb.x, hb.y, hb.z, hb.w};
        float s = acc[8][r] + gbt;
        #pragma unroll
        for (int k = 0; k < 8; k++) s += hv[k] * (acc[k][r] + gtv[k]);
        out[(size_t)(b0 + brow0 + r) * 128 + o] = s;
    }
}

extern "C" void kernel_launch(void* const* d_in, const int* in_sizes, int n_in,
                              void* d_out, int out_size, void* d_ws, size_t ws_size,
                              hipStream_t stream) {
    const float* x     = (const float*)d_in[0];
    const float* feat  = (const float*)d_in[1];
    const float* fc0W  = (const float*)d_in[2];
    const float* fc0b  = (const float*)d_in[3];
    const float* a0    = (const float*)d_in[4];
    const float* fc1W  = (const float*)d_in[5];
    const float* fc1b  = (const float*)d_in[6];
    const float* a1    = (const float*)d_in[7];
    const float* genW  = (const float*)d_in[8];
    const float* genb  = (const float*)d_in[9];
    float* out = (float*)d_out;

    // ===== MEASUREMENT PROBE (this round only) =====
    // The kernel's own rocprof row is occluded by ~40 us harness poison fills
    // (top-k cutoff), so its true duration K is invisible in counters.
    // The kernel is idempotent (pure function of const inputs -> out), so
    // launching it 3x is correctness-neutral and dur_us_new - 77.7 = 2*K.
    //   H1 (cycle model, K=3-6us): dur ~ 84-91  -> harness floor dominates.
    //   H2 (hidden slowness, K=25-35us): dur ~ 128-148 -> attack kernel.
    for (int rep = 0; rep < 3; ++rep) {
        hypernet_fused<<<256, 512, 0, stream>>>(
            x, feat, fc0W, fc0b, a0, fc1W, fc1b, a1, genW, genb, out);
    }
}

// Round 2
// 80.561 us; speedup vs baseline: 1.1497x; 1.1497x over previous
//
#include <hip/hip_runtime.h>
#include <hip/hip_bf16.h>

typedef __attribute__((ext_vector_type(8))) short short8;
typedef __attribute__((ext_vector_type(4))) float f32x4;
typedef __attribute__((ext_vector_type(2))) unsigned int u32x2;

#define NW 16384
#define SB_STRIDE_U 68   // uints per (o,k) row: 64 data (128 bf16) + 4 pad

union U8 { unsigned int u[4]; short8 s; };

static __device__ __forceinline__ unsigned int pkbf(float a, float b) {
    float2 t; t.x = a; t.y = b;
    __hip_bfloat162 h = __float22bfloat162_rn(t);   // v_cvt_pk_bf16_f32
    unsigned int r; __builtin_memcpy(&r, &h, 4);
    return r;
}

// grid = 512 blocks x 256 threads (4 waves), 2 blocks/CU.
// ot = blockIdx&7 (XCD round-robin: 64 blocks per XCD share one L2-resident
// 64KB genW slice), bg = blockIdx>>3 -> 64 b-rows per block, 16 per wave.
// Rationale vs previous 256x512: independent per-block barriers let block B's
// staging/MLP overlap block A's MFMA phase (latency hiding across blocks);
// the monolithic barrier no longer serializes the whole CU.
__global__ __launch_bounds__(256, 2) void hypernet_fused(
    const float* __restrict__ x,        // (4096,128)
    const float* __restrict__ feat,     // (4096,10)
    const float* __restrict__ fc0W, const float* __restrict__ fc0b,
    const float* __restrict__ a0p,
    const float* __restrict__ fc1W, const float* __restrict__ fc1b,
    const float* __restrict__ a1p,
    const float* __restrict__ genW,     // (16512,8)
    const float* __restrict__ genb,     // (16512)
    float* __restrict__ out)            // (4096,128)
{
    __shared__ __attribute__((aligned(16))) unsigned int sB32[16 * 9 * SB_STRIDE_U]; // 39168 B
    __shared__ float sH[64][8];                                                      // 2 KB

    const int tid  = threadIdx.x;
    const int ot   = blockIdx.x & 7;
    const int bg   = blockIdx.x >> 3;
    const int b0   = bg * 64;
    const int lane = tid & 63;
    const int w    = tid >> 6;          // wave 0..3
    const int quad = lane >> 4;
    const int o16  = lane & 15;
    const int o    = ot * 16 + o16;

    // ---- issue latency-critical independent loads EARLY ----
    float4 araw[8];
    const int arow = b0 + w * 16 + o16;
    #pragma unroll
    for (int kc = 0; kc < 4; kc++) {
        const float4* xp = (const float4*)(x + (size_t)arow * 128 + kc * 32 + quad * 8);
        araw[2 * kc]     = xp[0];
        araw[2 * kc + 1] = xp[1];
    }
    const float4* gt4 = (const float4*)(genW + (size_t)(NW + o) * 8);
    const float4 g0 = gt4[0], g1 = gt4[1];
    const float gbt = genb[NW + o];

    // ---- stage genW o-slice -> sB[o][k][i] bf16 (b64 writes) ----
    // 512 tasks (oo 0..15, iq 0..31): each converts 4 consecutive i-rows x 8 k
    // and writes one ds_write_b64 per k. LDS image identical to the verified
    // b32-write layout: uint index iq*2 holds bf16 pair (i0,i0+1), iq*2+1
    // holds (i0+2,i0+3).
    const float4* gw4 = (const float4*)(genW + (size_t)ot * 2048 * 8);
    #pragma unroll
    for (int j = 0; j < 2; j++) {
        const int idx = j * 256 + tid;              // [0,512)
        const int oo = idx >> 5, iq = idx & 31;
        const int base = (oo * 128 + iq * 4) * 2;
        const float4 r0a = gw4[base + 0], r0b = gw4[base + 1];  // i0:   k0..3, k4..7
        const float4 r1a = gw4[base + 2], r1b = gw4[base + 3];  // i0+1
        const float4 r2a = gw4[base + 4], r2b = gw4[base + 5];  // i0+2
        const float4 r3a = gw4[base + 6], r3b = gw4[base + 7];  // i0+3
        u32x2* dst = (u32x2*)(sB32 + oo * 9 * SB_STRIDE_U + iq * 2);  // k-stride = 34 u32x2
        u32x2 v;
        v[0] = pkbf(r0a.x, r1a.x); v[1] = pkbf(r2a.x, r3a.x); dst[0 * 34] = v;
        v[0] = pkbf(r0a.y, r1a.y); v[1] = pkbf(r2a.y, r3a.y); dst[1 * 34] = v;
        v[0] = pkbf(r0a.z, r1a.z); v[1] = pkbf(r2a.z, r3a.z); dst[2 * 34] = v;
        v[0] = pkbf(r0a.w, r1a.w); v[1] = pkbf(r2a.w, r3a.w); dst[3 * 34] = v;
        v[0] = pkbf(r0b.x, r1b.x); v[1] = pkbf(r2b.x, r3b.x); dst[4 * 34] = v;
        v[0] = pkbf(r0b.y, r1b.y); v[1] = pkbf(r2b.y, r3b.y); dst[5 * 34] = v;
        v[0] = pkbf(r0b.z, r1b.z); v[1] = pkbf(r2b.z, r3b.z); dst[6 * 34] = v;
        v[0] = pkbf(r0b.w, r1b.w); v[1] = pkbf(r2b.w, r3b.w); dst[7 * 34] = v;
    }
    // ---- genb o-slice -> k=8 plane: 512 tasks, float4 load + one b64 write ----
    const float4* gb4 = (const float4*)(genb + (size_t)ot * 2048);
    #pragma unroll
    for (int j = 0; j < 2; j++) {
        const int idx = j * 256 + tid;
        const int oo = idx >> 5, iq = idx & 31;
        const float4 p = gb4[oo * 32 + iq];
        u32x2 v; v[0] = pkbf(p.x, p.y); v[1] = pkbf(p.z, p.w);
        *(u32x2*)(sB32 + (oo * 9 + 8) * SB_STRIDE_U + iq * 2) = v;
    }
    // ---- tiny MLP -> sH (64 rows, one thread each) ----
    if (tid < 64) {
        const int b = b0 + tid;
        const float a0 = a0p[0], a1 = a1p[0];
        float fv[10];
        #pragma unroll
        for (int m = 0; m < 10; m++) fv[m] = feat[(size_t)b * 10 + m];
        float h0[16];
        #pragma unroll
        for (int jj = 0; jj < 16; jj++) {
            float t = fc0b[jj];
            #pragma unroll
            for (int m = 0; m < 10; m++) t += fc0W[jj * 10 + m] * fv[m];
            h0[jj] = (t >= 0.f) ? t : a0 * t;
        }
        #pragma unroll
        for (int n = 0; n < 8; n++) {
            float t = fc1b[n];
            #pragma unroll
            for (int jj = 0; jj < 16; jj++) t += fc1W[n * 16 + jj] * h0[jj];
            sH[tid][n] = (t >= 0.f) ? t : a1 * t;
        }
    }
    // ---- convert A-fragments (loads already landed) ----
    short8 a[4];
    #pragma unroll
    for (int kc = 0; kc < 4; kc++) {
        U8 t;
        const float4 va = araw[2 * kc], vb = araw[2 * kc + 1];
        t.u[0] = pkbf(va.x, va.y);
        t.u[1] = pkbf(va.z, va.w);
        t.u[2] = pkbf(vb.x, vb.y);
        t.u[3] = pkbf(vb.z, vb.w);
        a[kc] = t.s;
    }
    __syncthreads();

    // ---- main: 36 MFMAs per wave (16b x 16o x 9 k-planes, K=128) ----
    const unsigned short* sBs = (const unsigned short*)sB32;
    f32x4 acc[9];
    #pragma unroll
    for (int k = 0; k < 9; k++) acc[k] = (f32x4){0.f, 0.f, 0.f, 0.f};

    #pragma unroll
    for (int k = 0; k < 9; k++) {
        const unsigned short* bp = sBs + (o16 * 9 + k) * (SB_STRIDE_U * 2) + quad * 8;
        const short8 bv0 = *(const short8*)(bp);
        const short8 bv1 = *(const short8*)(bp + 32);
        const short8 bv2 = *(const short8*)(bp + 64);
        const short8 bv3 = *(const short8*)(bp + 96);
        acc[k] = __builtin_amdgcn_mfma_f32_16x16x32_bf16(a[0], bv0, acc[k], 0, 0, 0);
        acc[k] = __builtin_amdgcn_mfma_f32_16x16x32_bf16(a[1], bv1, acc[k], 0, 0, 0);
        acc[k] = __builtin_amdgcn_mfma_f32_16x16x32_bf16(a[2], bv2, acc[k], 0, 0, 0);
        acc[k] = __builtin_amdgcn_mfma_f32_16x16x32_bf16(a[3], bv3, acc[k], 0, 0, 0);
    }

    // ---- epilogue: out[b,o] = sum_{k<8} h1[b,k]*(Y_k + gW_tail[k]) + Y_8 + gb_tail ----
    const float gtv[8] = {g0.x, g0.y, g0.z, g0.w, g1.x, g1.y, g1.z, g1.w};
    const int brow0 = w * 16 + quad * 4;    // C/D: row = quad*4 + reg
    #pragma unroll
    for (int r = 0; r < 4; r++) {
        const float4* hp4 = (const float4*)sH[brow0 + r];
        const float4 ha = hp4[0], hb = hp4[1];
        const float hv[8] = {ha.x, ha.y, ha.z, ha.w, hb.x, hb.y, hb.z, hb.w};
        float s = acc[8][r] + gbt;
        #pragma unroll
        for (int k = 0; k < 8; k++) s += hv[k] * (acc[k][r] + gtv[k]);
        out[(size_t)(b0 + brow0 + r) * 128 + o] = s;
    }
}

extern "C" void kernel_launch(void* const* d_in, const int* in_sizes, int n_in,
                              void* d_out, int out_size, void* d_ws, size_t ws_size,
                              hipStream_t stream) {
    const float* x     = (const float*)d_in[0];
    const float* feat  = (const float*)d_in[1];
    const float* fc0W  = (const float*)d_in[2];
    const float* fc0b  = (const float*)d_in[3];
    const float* a0    = (const float*)d_in[4];
    const float* fc1W  = (const float*)d_in[5];
    const float* fc1b  = (const float*)d_in[6];
    const float* a1    = (const float*)d_in[7];
    const float* genW  = (const float*)d_in[8];
    const float* genb  = (const float*)d_in[9];
    float* out = (float*)d_out;

    hypernet_fused<<<512, 256, 0, stream>>>(
        x, feat, fc0W, fc0b, a0, fc1W, fc1b, a1, genW, genb, out);
}

// Round 3
// 77.551 us; speedup vs baseline: 1.1944x; 1.0388x over previous
//
#include <hip/hip_runtime.h>
#include <hip/hip_bf16.h>

typedef __attribute__((ext_vector_type(8))) short short8;
typedef __attribute__((ext_vector_type(4))) float f32x4;

#define NW 16384
#define SB_STRIDE_U 68   // uints per (o,k) row: 64 data (128 bf16) + 4 pad

union U8 { unsigned int u[4]; short8 s; };

static __device__ __forceinline__ unsigned int pkbf(float a, float b) {
    float2 t; t.x = a; t.y = b;
    __hip_bfloat162 h = __float22bfloat162_rn(t);   // v_cvt_pk_bf16_f32
    unsigned int r; __builtin_memcpy(&r, &h, 4);
    return r;
}

// ============================================================================
// VERIFIED STRUCTURE (77.70 us r0, 78.0 us prior session). Do not restructure:
//  - R1 probe (3x launch): marginal K = 7.46 us/launch; harness floor 70.2 us.
//  - R2 experiment (512x256, 2 blk/CU, per-thread i-quad staging): 80.56 us,
//    -2.9 us regression. Instruction-count delta was ~0.06 us, so the loss is
//    structural: 128B-lane-stride (uncoalesced) genW staging loads and/or two
//    4-wave blocks hiding cold-miss latency worse than one 8-wave block.
//    Poison fill (268 MB) blows L2/L3 every iteration -> genW/x always cold.
//  - 1 block/CU, 8 waves, single barrier, 64B-stride staging = local optimum.
// grid = 256 blocks x 512 threads. ot = blockIdx&7 (XCD round-robin: 32 blocks
// per XCD share one L2-resident 64KB genW slice), bg = blockIdx>>3
// -> 128 b-rows per block, 16 per wave.
// ============================================================================
__global__ __launch_bounds__(512, 2) void hypernet_fused(
    const float* __restrict__ x,        // (4096,128)
    const float* __restrict__ feat,     // (4096,10)
    const float* __restrict__ fc0W, const float* __restrict__ fc0b,
    const float* __restrict__ a0p,
    const float* __restrict__ fc1W, const float* __restrict__ fc1b,
    const float* __restrict__ a1p,
    const float* __restrict__ genW,     // (16512,8)
    const float* __restrict__ genb,     // (16512)
    float* __restrict__ out)            // (4096,128)
{
    __shared__ __attribute__((aligned(16))) unsigned int sB32[16 * 9 * SB_STRIDE_U]; // 39168 B
    __shared__ float sH[128][8];                                                     // 4 KB

    const int tid  = threadIdx.x;
    const int ot   = blockIdx.x & 7;
    const int bg   = blockIdx.x >> 3;
    const int b0   = bg * 128;
    const int lane = tid & 63;
    const int w    = tid >> 6;          // wave 0..7
    const int quad = lane >> 4;
    const int o16  = lane & 15;
    const int o    = ot * 16 + o16;

    // ---- issue latency-critical independent loads EARLY ----
    float4 araw[8];
    const int arow = b0 + w * 16 + o16;
    #pragma unroll
    for (int kc = 0; kc < 4; kc++) {
        const float4* xp = (const float4*)(x + (size_t)arow * 128 + kc * 32 + quad * 8);
        araw[2 * kc]     = xp[0];
        araw[2 * kc + 1] = xp[1];
    }
    const float4* gt4 = (const float4*)(genW + (size_t)(NW + o) * 8);
    const float4 g0 = gt4[0], g1 = gt4[1];
    const float gbt = genb[NW + o];

    // ---- stage genW o-slice -> sB[o][k][i] bf16; paired-i b32 writes ----
    // 16 o x 128 i rows of 8 k-floats = 1024 i-pairs; 512 threads -> 2 each
    const float4* gw4 = (const float4*)(genW + (size_t)ot * 2048 * 8);
    #pragma unroll
    for (int j = 0; j < 2; j++) {
        const int idx = j * 512 + tid;              // [0,1024): oo = idx>>6, ip = idx&63
        const int oo = idx >> 6, ip = idx & 63;
        const int f4 = (oo * 128 + 2 * ip) * 2;
        const float4 p0 = gw4[f4], p1 = gw4[f4 + 1];     // i:   k0..3, k4..7
        const float4 q0 = gw4[f4 + 2], q1 = gw4[f4 + 3]; // i+1: k0..3, k4..7
        unsigned int* dst = sB32 + oo * 9 * SB_STRIDE_U + ip;
        dst[0 * SB_STRIDE_U] = pkbf(p0.x, q0.x);
        dst[1 * SB_STRIDE_U] = pkbf(p0.y, q0.y);
        dst[2 * SB_STRIDE_U] = pkbf(p0.z, q0.z);
        dst[3 * SB_STRIDE_U] = pkbf(p0.w, q0.w);
        dst[4 * SB_STRIDE_U] = pkbf(p1.x, q1.x);
        dst[5 * SB_STRIDE_U] = pkbf(p1.y, q1.y);
        dst[6 * SB_STRIDE_U] = pkbf(p1.z, q1.z);
        dst[7 * SB_STRIDE_U] = pkbf(p1.w, q1.w);
    }
    // ---- genb o-slice -> k=8 plane (1024 float2, 2 per thread) ----
    const float2* gb2 = (const float2*)(genb + (size_t)ot * 2048);
    #pragma unroll
    for (int j = 0; j < 2; j++) {
        const int idx = j * 512 + tid;
        const int oo = idx >> 6, ip = idx & 63;
        const float2 p = gb2[oo * 64 + ip];
        sB32[(oo * 9 + 8) * SB_STRIDE_U + ip] = pkbf(p.x, p.y);
    }
    // ---- tiny MLP -> sH (128 rows, one thread each) ----
    if (tid < 128) {
        const int b = b0 + tid;
        const float a0 = a0p[0], a1 = a1p[0];
        float fv[10];
        #pragma unroll
        for (int m = 0; m < 10; m++) fv[m] = feat[(size_t)b * 10 + m];
        float h0[16];
        #pragma unroll
        for (int jj = 0; jj < 16; jj++) {
            float t = fc0b[jj];
            #pragma unroll
            for (int m = 0; m < 10; m++) t += fc0W[jj * 10 + m] * fv[m];
            h0[jj] = (t >= 0.f) ? t : a0 * t;
        }
        #pragma unroll
        for (int n = 0; n < 8; n++) {
            float t = fc1b[n];
            #pragma unroll
            for (int jj = 0; jj < 16; jj++) t += fc1W[n * 16 + jj] * h0[jj];
            sH[tid][n] = (t >= 0.f) ? t : a1 * t;
        }
    }
    // ---- convert A-fragments (loads already landed) ----
    short8 a[4];
    #pragma unroll
    for (int kc = 0; kc < 4; kc++) {
        U8 t;
        const float4 va = araw[2 * kc], vb = araw[2 * kc + 1];
        t.u[0] = pkbf(va.x, va.y);
        t.u[1] = pkbf(va.z, va.w);
        t.u[2] = pkbf(vb.x, vb.y);
        t.u[3] = pkbf(vb.z, vb.w);
        a[kc] = t.s;
    }
    __syncthreads();

    // ---- main: 36 MFMAs per wave (16b x 16o x 9 k-planes, K=128) ----
    const unsigned short* sBs = (const unsigned short*)sB32;
    f32x4 acc[9];
    #pragma unroll
    for (int k = 0; k < 9; k++) acc[k] = (f32x4){0.f, 0.f, 0.f, 0.f};

    #pragma unroll
    for (int k = 0; k < 9; k++) {
        const unsigned short* bp = sBs + (o16 * 9 + k) * (SB_STRIDE_U * 2) + quad * 8;
        const short8 bv0 = *(const short8*)(bp);
        const short8 bv1 = *(const short8*)(bp + 32);
        const short8 bv2 = *(const short8*)(bp + 64);
        const short8 bv3 = *(const short8*)(bp + 96);
        acc[k] = __builtin_amdgcn_mfma_f32_16x16x32_bf16(a[0], bv0, acc[k], 0, 0, 0);
        acc[k] = __builtin_amdgcn_mfma_f32_16x16x32_bf16(a[1], bv1, acc[k], 0, 0, 0);
        acc[k] = __builtin_amdgcn_mfma_f32_16x16x32_bf16(a[2], bv2, acc[k], 0, 0, 0);
        acc[k] = __builtin_amdgcn_mfma_f32_16x16x32_bf16(a[3], bv3, acc[k], 0, 0, 0);
    }

    // ---- epilogue: out[b,o] = sum_{k<8} h1[b,k]*(Y_k + gW_tail[k]) + Y_8 + gb_tail ----
    const float gtv[8] = {g0.x, g0.y, g0.z, g0.w, g1.x, g1.y, g1.z, g1.w};
    const int brow0 = w * 16 + quad * 4;    // C/D: row = quad*4 + reg
    #pragma unroll
    for (int r = 0; r < 4; r++) {
        const float4* hp4 = (const float4*)sH[brow0 + r];
        const float4 ha = hp4[0], hb = hp4[1];
        const float hv[8] = {ha.x, ha.y, ha.z, ha.w, hb.x, hb.y, hb.z, hb.w};
        float s = acc[8][r] + gbt;
        #pragma unroll
        for (int k = 0; k < 8; k++) s += hv[k] * (acc[k][r] + gtv[k]);
        out[(size_t)(b0 + brow0 + r) * 128 + o] = s;
    }
}

extern "C" void kernel_launch(void* const* d_in, const int* in_sizes, int n_in,
                              void* d_out, int out_size, void* d_ws, size_t ws_size,
                              hipStream_t stream) {
    const float* x     = (const float*)d_in[0];
    const float* feat  = (const float*)d_in[1];
    const float* fc0W  = (const float*)d_in[2];
    const float* fc0b  = (const float*)d_in[3];
    const float* a0    = (const float*)d_in[4];
    const float* fc1W  = (const float*)d_in[5];
    const float* fc1b  = (const float*)d_in[6];
    const float* a1    = (const float*)d_in[7];
    const float* genW  = (const float*)d_in[8];
    const float* genb  = (const float*)d_in[9];
    float* out = (float*)d_out;

    hypernet_fused<<<256, 512, 0, stream>>>(
        x, feat, fc0W, fc0b, a0, fc1W, fc1b, a1, genW, genb, out);
}